// Round 4
// baseline (79.276 us; speedup 1.0000x reference)
//
#include <hip/hip_runtime.h>
#include <hip/hip_bf16.h>

#define NSEG 512
#define EPSF 1e-6f
#define MAIN_GRID 1024
#define MAIN_BLOCK 256
#define WAVES_PER_BLOCK 4

// d_ws layout:
//   [0, 16KB)          : gacc f64[2048]  ([0..511]=count, [512..1023]=sum_x,
//                        [1024..1535]=sum_log, [1536..2047]=sum_log2)
//   [16KB, 16KB+8MB)   : per-block f32 partials, entry layout e = s*4+f

__global__ __launch_bounds__(1024) void zero_ws_kernel(double* __restrict__ g) {
    int i = blockIdx.x * blockDim.x + threadIdx.x;
    if (i < 4 * NSEG) g[i] = 0.0;
}

__global__ __launch_bounds__(MAIN_BLOCK) void seg_stats_kernel(const float4* __restrict__ x4,
                                                               const int4* __restrict__ i4,
                                                               float* __restrict__ parts,
                                                               double* __restrict__ gacc,
                                                               int n4, int use_parts) {
    // Per-wave private histogram; duplicates resolved in REGISTERS via
    // 9-ballot match-any -> rank/multiplicity. No LDS tag, no atomics.
    __shared__ float hist[WAVES_PER_BLOCK][NSEG * 4];

    const int wave = threadIdx.x >> 6;
    const int lane = threadIdx.x & 63;
    float* h = hist[wave];
    const unsigned long long lt_mask = (1ull << lane) - 1ull;

    for (int i = threadIdx.x; i < WAVES_PER_BLOCK * NSEG * 4; i += MAIN_BLOCK)
        ((float*)hist)[i] = 0.0f;
    __syncthreads();

    const int stride = gridDim.x * blockDim.x;
    for (int i = blockIdx.x * blockDim.x + threadIdx.x; i < n4; i += stride) {
        float4 xv = x4[i];
        int4 iv = i4[i];
#pragma unroll
        for (int c = 0; c < 4; ++c) {
            float v = (c == 0) ? xv.x : (c == 1) ? xv.y : (c == 2) ? xv.z : xv.w;
            int s   = (c == 0) ? iv.x : (c == 1) ? iv.y : (c == 2) ? iv.z : iv.w;
            float lx = __logf(fabsf(v) + EPSF);
            float l2 = lx * lx;

            // match-any over the 9-bit segment id: mask of lanes with same s
            unsigned long long m = ~0ull;
#pragma unroll
            for (int b = 0; b < 9; ++b) {
                unsigned long long bb = __ballot(((unsigned)s >> b) & 1u);
                m &= (((unsigned)s >> b) & 1u) ? bb : ~bb;
            }
            int rank = __popcll(m & lt_mask);     // my order among duplicates
            int mult = __popcll(m);               // duplicate-set size
            float cadd = (rank == 0) ? (float)mult : 0.0f;

            // round r: lanes with rank==r do a plain b128 RMW (conflict-free
            // by construction within the wave; DS pipe keeps per-wave order)
            for (int r = 0;; ++r) {
                if (!__ballot(rank >= r)) break;
                if (rank == r) {
                    float4 hv = *(float4*)(h + (s << 2));
                    hv.x += cadd;
                    hv.y += v;
                    hv.z += lx;
                    hv.w += l2;
                    *(float4*)(h + (s << 2)) = hv;
                }
            }
        }
    }
    __syncthreads();

    // Combine the 4 wave copies; flush per block.
    for (int e = threadIdx.x; e < NSEG * 4; e += MAIN_BLOCK) {
        float s0 = hist[0][e] + hist[1][e] + hist[2][e] + hist[3][e];
        if (use_parts) {
            parts[blockIdx.x * (NSEG * 4) + e] = s0;
        } else if (s0 != 0.0f) {
            unsafeAtomicAdd(&gacc[(e & 3) * NSEG + (e >> 2)], (double)s0);
        }
    }
}

#define RP_CHUNKS 16  // 1024 partial blocks / 64 per chunk
__global__ __launch_bounds__(256) void reduce_partials_kernel(const float* __restrict__ parts,
                                                              double* __restrict__ gacc) {
    int eg = blockIdx.x & 7;
    int bc = blockIdx.x >> 3;
    int e = eg * 256 + threadIdx.x;  // 0..2047, entry layout s*4+f
    int b0 = bc * (MAIN_GRID / RP_CHUNKS);
    double acc = 0.0;
    for (int b = 0; b < MAIN_GRID / RP_CHUNKS; ++b)
        acc += (double)parts[(size_t)(b0 + b) * (NSEG * 4) + e];
    unsafeAtomicAdd(&gacc[(e & 3) * NSEG + (e >> 2)], acc);
}

__global__ __launch_bounds__(512) void finalize_kernel(const double* __restrict__ gacc,
                                                       const float* __restrict__ tmean,
                                                       const float* __restrict__ tstd,
                                                       float* __restrict__ out) {
    int s = threadIdx.x;  // 512 threads, one per segment
    double cnt = gacc[s];
    double c = cnt > 1.0 ? cnt : 1.0;
    double mean_w = gacc[NSEG + s] / c;
    double mean_log = gacc[2 * NSEG + s] / c;
    double var = gacc[3 * NSEG + s] / c - mean_log * mean_log;
    if (var < 0.0) var = 0.0;
    double std_w = sqrt(var + 1e-6);
    double dm = mean_w - (double)tmean[s];
    double dsd = std_w - (double)tstd[s];
    double term = 0.5 * dm * dm + 0.5 * dsd * dsd;

#pragma unroll
    for (int off = 32; off > 0; off >>= 1) term += __shfl_down(term, off, 64);

    __shared__ double part[8];
    int wid = threadIdx.x >> 6;
    if ((threadIdx.x & 63) == 0) part[wid] = term;
    __syncthreads();
    if (threadIdx.x == 0) {
        double t = 0.0;
#pragma unroll
        for (int i = 0; i < 8; ++i) t += part[i];
        out[0] = (float)((t / (double)NSEG) * 0.01);
    }
}

extern "C" void kernel_launch(void* const* d_in, const int* in_sizes, int n_in,
                              void* d_out, int out_size, void* d_ws, size_t ws_size,
                              hipStream_t stream) {
    const float* x = (const float*)d_in[0];
    const int* idx = (const int*)d_in[1];
    const float* tmean = (const float*)d_in[2];
    const float* tstd = (const float*)d_in[3];
    float* out = (float*)d_out;

    double* gacc = (double*)d_ws;
    float* parts = (float*)((char*)d_ws + 4 * NSEG * sizeof(double));
    size_t need = 4 * NSEG * sizeof(double) + (size_t)MAIN_GRID * NSEG * 4 * sizeof(float);
    int use_parts = (ws_size >= need) ? 1 : 0;

    int n = in_sizes[0];
    int n4 = n / 4;  // N_EDGES = 16777216, divisible by 4

    zero_ws_kernel<<<2, 1024, 0, stream>>>(gacc);
    seg_stats_kernel<<<MAIN_GRID, MAIN_BLOCK, 0, stream>>>((const float4*)x, (const int4*)idx,
                                                           parts, gacc, n4, use_parts);
    if (use_parts)
        reduce_partials_kernel<<<8 * RP_CHUNKS, 256, 0, stream>>>(parts, gacc);
    finalize_kernel<<<1, 512, 0, stream>>>(gacc, tmean, tstd, out);
}

// Round 5
// 73.379 us; speedup vs baseline: 1.0804x; 1.0804x over previous
//
#include <hip/hip_runtime.h>
#include <hip/hip_bf16.h>

#define NSEG 512
#define EPSF 1e-6f
#define MAIN_GRID 1024
#define MAIN_BLOCK 256
#define WAVES_PER_BLOCK 4

// d_ws layout:
//   [0, 16KB)          : gacc f64[2048]  ([0..511]=count, [512..1023]=sum_x,
//                        [1024..1535]=sum_log, [1536..2047]=sum_log2)
//   [16KB, 16KB+8MB)   : per-block f32 partials, entry layout e = s*4+f

__global__ __launch_bounds__(1024) void zero_ws_kernel(double* __restrict__ g) {
    int i = blockIdx.x * blockDim.x + threadIdx.x;
    if (i < 4 * NSEG) g[i] = 0.0;
}

__global__ __launch_bounds__(MAIN_BLOCK) void seg_stats_kernel(const float4* __restrict__ x4,
                                                               const int4* __restrict__ i4,
                                                               float* __restrict__ parts,
                                                               double* __restrict__ gacc,
                                                               int n4, int use_parts) {
    // Per-wave private histogram (float4 per segment) + ONE u16 tag array per
    // wave shared by all 4 channels. Election code = (channel<<6)|lane is
    // unique per (lane,channel) item -> exactly one winner per segment per
    // round across channels -> no RMW races, 4 concurrent latency chains.
    __shared__ float4 hist4[WAVES_PER_BLOCK][NSEG];
    __shared__ unsigned short tag[WAVES_PER_BLOCK][NSEG];

    const int wave = threadIdx.x >> 6;
    const int lane = threadIdx.x & 63;
    float4* h = hist4[wave];
    volatile unsigned short* tg = tag[wave];  // force real ds_write/ds_read

    for (int i = threadIdx.x; i < WAVES_PER_BLOCK * NSEG; i += MAIN_BLOCK)
        ((float4*)hist4)[i] = make_float4(0.f, 0.f, 0.f, 0.f);
    __syncthreads();

    const int stride = gridDim.x * blockDim.x;
    for (int i = blockIdx.x * blockDim.x + threadIdx.x; i < n4; i += stride) {
        float4 xv = x4[i];
        int4 iv = i4[i];
        float v[4] = {xv.x, xv.y, xv.z, xv.w};
        int s[4] = {iv.x, iv.y, iv.z, iv.w};
        float lx[4], l2[4];
        unsigned short code[4];
#pragma unroll
        for (int c = 0; c < 4; ++c) {
            lx[c] = __logf(fabsf(v[c]) + EPSF);
            l2[c] = lx[c] * lx[c];
            code[c] = (unsigned short)((c << 6) | lane);
        }

        unsigned done = 0;  // bit c set when channel c has been accumulated
        while (__ballot(done != 0xFu)) {
            // phase 1: all active items write their code (last write wins)
#pragma unroll
            for (int c = 0; c < 4; ++c)
                if (!(done & (1u << c))) tg[s[c]] = code[c];
            // phase 2: all active items read back (DS pipe is per-wave ordered)
            unsigned short w[4];
#pragma unroll
            for (int c = 0; c < 4; ++c)
                w[c] = (done & (1u << c)) ? (unsigned short)0xFFFF : tg[s[c]];
            // phase 3: unique winners do a plain b128 RMW
#pragma unroll
            for (int c = 0; c < 4; ++c) {
                if (!(done & (1u << c)) && w[c] == code[c]) {
                    float4 hv = h[s[c]];
                    hv.x += 1.0f;
                    hv.y += v[c];
                    hv.z += lx[c];
                    hv.w += l2[c];
                    h[s[c]] = hv;
                    done |= (1u << c);
                }
            }
        }
    }
    __syncthreads();

    // Combine the 4 wave copies; flush per block (float4 = entry layout s*4+f).
    for (int sg = threadIdx.x; sg < NSEG; sg += MAIN_BLOCK) {
        float4 a = hist4[0][sg];
        float4 b = hist4[1][sg];
        float4 cc = hist4[2][sg];
        float4 d = hist4[3][sg];
        float4 t = make_float4(a.x + b.x + cc.x + d.x, a.y + b.y + cc.y + d.y,
                               a.z + b.z + cc.z + d.z, a.w + b.w + cc.w + d.w);
        if (use_parts) {
            *(float4*)(parts + (size_t)blockIdx.x * (NSEG * 4) + (sg << 2)) = t;
        } else {
            if (t.x != 0.0f) unsafeAtomicAdd(&gacc[0 * NSEG + sg], (double)t.x);
            if (t.y != 0.0f) unsafeAtomicAdd(&gacc[1 * NSEG + sg], (double)t.y);
            if (t.z != 0.0f) unsafeAtomicAdd(&gacc[2 * NSEG + sg], (double)t.z);
            if (t.w != 0.0f) unsafeAtomicAdd(&gacc[3 * NSEG + sg], (double)t.w);
        }
    }
}

#define RP_CHUNKS 16  // 1024 partial blocks / 64 per chunk
__global__ __launch_bounds__(256) void reduce_partials_kernel(const float* __restrict__ parts,
                                                              double* __restrict__ gacc) {
    int eg = blockIdx.x & 7;
    int bc = blockIdx.x >> 3;
    int e = eg * 256 + threadIdx.x;  // 0..2047, entry layout s*4+f
    int b0 = bc * (MAIN_GRID / RP_CHUNKS);
    double acc = 0.0;
    for (int b = 0; b < MAIN_GRID / RP_CHUNKS; ++b)
        acc += (double)parts[(size_t)(b0 + b) * (NSEG * 4) + e];
    unsafeAtomicAdd(&gacc[(e & 3) * NSEG + (e >> 2)], acc);
}

__global__ __launch_bounds__(512) void finalize_kernel(const double* __restrict__ gacc,
                                                       const float* __restrict__ tmean,
                                                       const float* __restrict__ tstd,
                                                       float* __restrict__ out) {
    int s = threadIdx.x;  // 512 threads, one per segment
    double cnt = gacc[s];
    double c = cnt > 1.0 ? cnt : 1.0;
    double mean_w = gacc[NSEG + s] / c;
    double mean_log = gacc[2 * NSEG + s] / c;
    double var = gacc[3 * NSEG + s] / c - mean_log * mean_log;
    if (var < 0.0) var = 0.0;
    double std_w = sqrt(var + 1e-6);
    double dm = mean_w - (double)tmean[s];
    double dsd = std_w - (double)tstd[s];
    double term = 0.5 * dm * dm + 0.5 * dsd * dsd;

#pragma unroll
    for (int off = 32; off > 0; off >>= 1) term += __shfl_down(term, off, 64);

    __shared__ double part[8];
    int wid = threadIdx.x >> 6;
    if ((threadIdx.x & 63) == 0) part[wid] = term;
    __syncthreads();
    if (threadIdx.x == 0) {
        double t = 0.0;
#pragma unroll
        for (int i = 0; i < 8; ++i) t += part[i];
        out[0] = (float)((t / (double)NSEG) * 0.01);
    }
}

extern "C" void kernel_launch(void* const* d_in, const int* in_sizes, int n_in,
                              void* d_out, int out_size, void* d_ws, size_t ws_size,
                              hipStream_t stream) {
    const float* x = (const float*)d_in[0];
    const int* idx = (const int*)d_in[1];
    const float* tmean = (const float*)d_in[2];
    const float* tstd = (const float*)d_in[3];
    float* out = (float*)d_out;

    double* gacc = (double*)d_ws;
    float* parts = (float*)((char*)d_ws + 4 * NSEG * sizeof(double));
    size_t need = 4 * NSEG * sizeof(double) + (size_t)MAIN_GRID * NSEG * 4 * sizeof(float);
    int use_parts = (ws_size >= need) ? 1 : 0;

    int n = in_sizes[0];
    int n4 = n / 4;  // N_EDGES = 16777216, divisible by 4

    zero_ws_kernel<<<2, 1024, 0, stream>>>(gacc);
    seg_stats_kernel<<<MAIN_GRID, MAIN_BLOCK, 0, stream>>>((const float4*)x, (const int4*)idx,
                                                           parts, gacc, n4, use_parts);
    if (use_parts)
        reduce_partials_kernel<<<8 * RP_CHUNKS, 256, 0, stream>>>(parts, gacc);
    finalize_kernel<<<1, 512, 0, stream>>>(gacc, tmean, tstd, out);
}

// Round 6
// 66.076 us; speedup vs baseline: 1.1998x; 1.1105x over previous
//
#include <hip/hip_runtime.h>
#include <hip/hip_bf16.h>

#define NSEG 512
#define EPSF 1e-6f
#define MAIN_GRID 1024
#define MAIN_BLOCK 256
#define WAVES_PER_BLOCK 4

// d_ws layout:
//   [0, 16KB)          : gacc f64[2048]  ([0..511]=count, [512..1023]=sum_x,
//                        [1024..1535]=sum_log, [1536..2047]=sum_log2)
//   [16KB, 16KB+8MB)   : per-block f32 partials, entry layout e = s*4+f

__global__ __launch_bounds__(1024) void zero_ws_kernel(double* __restrict__ g) {
    int i = blockIdx.x * blockDim.x + threadIdx.x;
    if (i < 4 * NSEG) g[i] = 0.0;
}

__global__ __launch_bounds__(MAIN_BLOCK) void seg_stats_kernel(const float4* __restrict__ x4,
                                                               const int4* __restrict__ i4,
                                                               float* __restrict__ parts,
                                                               double* __restrict__ gacc,
                                                               int n4, int use_parts) {
    // Per-wave private histogram + u8 tag election shared by all 4 channels.
    // Each round = ONE LDS round-trip: {tagW x4} | clobber | {tagR x4 +
    // speculative histR x4, one wait} | winners RMW. Per-wave DS ordering
    // makes speculative reads and round r+1 reads correct without fences.
    __shared__ float4 hist4[WAVES_PER_BLOCK][NSEG];
    __shared__ unsigned char tag[WAVES_PER_BLOCK][NSEG];

    const int wave = threadIdx.x >> 6;
    const int lane = threadIdx.x & 63;
    float4* h = hist4[wave];
    unsigned char* tg = tag[wave];

    for (int i = threadIdx.x; i < WAVES_PER_BLOCK * NSEG; i += MAIN_BLOCK)
        ((float4*)hist4)[i] = make_float4(0.f, 0.f, 0.f, 0.f);
    __syncthreads();

    const int stride = gridDim.x * blockDim.x;
    int i = blockIdx.x * blockDim.x + threadIdx.x;
    if (i < n4) {
        float4 xv = x4[i];
        int4 iv = i4[i];
        while (true) {
            // prefetch next iteration's data (issued before any clobber)
            int inext = i + stride;
            bool more = inext < n4;
            float4 xv_n;
            int4 iv_n;
            if (more) {
                xv_n = x4[inext];
                iv_n = i4[inext];
            }

            float v[4] = {xv.x, xv.y, xv.z, xv.w};
            int s[4] = {iv.x, iv.y, iv.z, iv.w};
            float lx[4], l2[4];
            unsigned char code[4];
#pragma unroll
            for (int c = 0; c < 4; ++c) {
                lx[c] = __logf(fabsf(v[c]) + EPSF);
                l2[c] = lx[c] * lx[c];
                code[c] = (unsigned char)((c << 6) | lane);
            }

            unsigned active = 0xFu;
            while (true) {
                // phase 1: active items write their unique code (last wins)
#pragma unroll
                for (int c = 0; c < 4; ++c)
                    if (active & (1u << c)) tg[s[c]] = code[c];
                __asm__ volatile("" ::: "memory");
                // phase 2: batched tag read-back + SPECULATIVE hist read;
                // compiler emits one combined lgkmcnt wait.
                unsigned char w[4] = {0, 0, 0, 0};
                float4 hv[4];
#pragma unroll
                for (int c = 0; c < 4; ++c)
                    if (active & (1u << c)) {
                        w[c] = tg[s[c]];
                        hv[c] = h[s[c]];
                    }
                __asm__ volatile("" ::: "memory");
                // phase 3: unique winners commit the RMW; losers retry
                unsigned next = 0;
#pragma unroll
                for (int c = 0; c < 4; ++c) {
                    if (active & (1u << c)) {
                        if (w[c] == code[c]) {
                            hv[c].x += 1.0f;
                            hv[c].y += v[c];
                            hv[c].z += lx[c];
                            hv[c].w += l2[c];
                            h[s[c]] = hv[c];
                        } else {
                            next |= (1u << c);
                        }
                    }
                }
                active = next;
                if (!__ballot(active != 0)) break;
            }

            if (!__ballot(more)) break;
            i = inext;
            xv = xv_n;
            iv = iv_n;
        }
    }
    __syncthreads();

    // Combine the 4 wave copies; flush per block (float4 = entry layout s*4+f).
    for (int sg = threadIdx.x; sg < NSEG; sg += MAIN_BLOCK) {
        float4 a = hist4[0][sg];
        float4 b = hist4[1][sg];
        float4 cc = hist4[2][sg];
        float4 d = hist4[3][sg];
        float4 t = make_float4(a.x + b.x + cc.x + d.x, a.y + b.y + cc.y + d.y,
                               a.z + b.z + cc.z + d.z, a.w + b.w + cc.w + d.w);
        if (use_parts) {
            *(float4*)(parts + (size_t)blockIdx.x * (NSEG * 4) + (sg << 2)) = t;
        } else {
            if (t.x != 0.0f) unsafeAtomicAdd(&gacc[0 * NSEG + sg], (double)t.x);
            if (t.y != 0.0f) unsafeAtomicAdd(&gacc[1 * NSEG + sg], (double)t.y);
            if (t.z != 0.0f) unsafeAtomicAdd(&gacc[2 * NSEG + sg], (double)t.z);
            if (t.w != 0.0f) unsafeAtomicAdd(&gacc[3 * NSEG + sg], (double)t.w);
        }
    }
}

#define RP_CHUNKS 16  // 1024 partial blocks / 64 per chunk
__global__ __launch_bounds__(256) void reduce_partials_kernel(const float* __restrict__ parts,
                                                              double* __restrict__ gacc) {
    int eg = blockIdx.x & 7;
    int bc = blockIdx.x >> 3;
    int e = eg * 256 + threadIdx.x;  // 0..2047, entry layout s*4+f
    int b0 = bc * (MAIN_GRID / RP_CHUNKS);
    double acc = 0.0;
    for (int b = 0; b < MAIN_GRID / RP_CHUNKS; ++b)
        acc += (double)parts[(size_t)(b0 + b) * (NSEG * 4) + e];
    unsafeAtomicAdd(&gacc[(e & 3) * NSEG + (e >> 2)], acc);
}

__global__ __launch_bounds__(512) void finalize_kernel(const double* __restrict__ gacc,
                                                       const float* __restrict__ tmean,
                                                       const float* __restrict__ tstd,
                                                       float* __restrict__ out) {
    int s = threadIdx.x;  // 512 threads, one per segment
    double cnt = gacc[s];
    double c = cnt > 1.0 ? cnt : 1.0;
    double mean_w = gacc[NSEG + s] / c;
    double mean_log = gacc[2 * NSEG + s] / c;
    double var = gacc[3 * NSEG + s] / c - mean_log * mean_log;
    if (var < 0.0) var = 0.0;
    double std_w = sqrt(var + 1e-6);
    double dm = mean_w - (double)tmean[s];
    double dsd = std_w - (double)tstd[s];
    double term = 0.5 * dm * dm + 0.5 * dsd * dsd;

#pragma unroll
    for (int off = 32; off > 0; off >>= 1) term += __shfl_down(term, off, 64);

    __shared__ double part[8];
    int wid = threadIdx.x >> 6;
    if ((threadIdx.x & 63) == 0) part[wid] = term;
    __syncthreads();
    if (threadIdx.x == 0) {
        double t = 0.0;
#pragma unroll
        for (int i = 0; i < 8; ++i) t += part[i];
        out[0] = (float)((t / (double)NSEG) * 0.01);
    }
}

extern "C" void kernel_launch(void* const* d_in, const int* in_sizes, int n_in,
                              void* d_out, int out_size, void* d_ws, size_t ws_size,
                              hipStream_t stream) {
    const float* x = (const float*)d_in[0];
    const int* idx = (const int*)d_in[1];
    const float* tmean = (const float*)d_in[2];
    const float* tstd = (const float*)d_in[3];
    float* out = (float*)d_out;

    double* gacc = (double*)d_ws;
    float* parts = (float*)((char*)d_ws + 4 * NSEG * sizeof(double));
    size_t need = 4 * NSEG * sizeof(double) + (size_t)MAIN_GRID * NSEG * 4 * sizeof(float);
    int use_parts = (ws_size >= need) ? 1 : 0;

    int n = in_sizes[0];
    int n4 = n / 4;  // N_EDGES = 16777216, divisible by 4

    zero_ws_kernel<<<2, 1024, 0, stream>>>(gacc);
    seg_stats_kernel<<<MAIN_GRID, MAIN_BLOCK, 0, stream>>>((const float4*)x, (const int4*)idx,
                                                           parts, gacc, n4, use_parts);
    if (use_parts)
        reduce_partials_kernel<<<8 * RP_CHUNKS, 256, 0, stream>>>(parts, gacc);
    finalize_kernel<<<1, 512, 0, stream>>>(gacc, tmean, tstd, out);
}